// Round 13
// baseline (278.392 us; speedup 1.0000x reference)
//
#include <hip/hip_runtime.h>
#include <hip/hip_bf16.h>
#include <stdint.h>

#define T_SEQ 2048
#define D_MODEL 2048
#define N_HEADS 16
#define HEAD_DIM 128

typedef __hip_bfloat16 bf16_t;
typedef __attribute__((ext_vector_type(8))) short short8;
typedef __attribute__((ext_vector_type(4))) short short4v;
typedef __attribute__((ext_vector_type(4))) float f32x4;
typedef __attribute__((ext_vector_type(16))) float f32x16;

__device__ __forceinline__ unsigned short f2bf(float x) {
  union { float f; unsigned u; } c; c.f = x;
  unsigned u = c.u;
  u += 0x7fffu + ((u >> 16) & 1u);   // RNE
  return (unsigned short)(u >> 16);
}
__device__ __forceinline__ float bf2f(short v) {
  union { unsigned u; float f; } c;
  c.u = ((unsigned)(unsigned short)v) << 16;
  return c.f;
}
__device__ __forceinline__ void async16(const bf16_t* g, bf16_t* l) {
  __builtin_amdgcn_global_load_lds(
      (const __attribute__((address_space(1))) void*)g,
      (__attribute__((address_space(3))) void*)l, 16, 0, 0);
}

// ---------------- f32 -> bf16 conversion ----------------
__global__ __launch_bounds__(256) void cvt_kernel(const float* __restrict__ in,
                                                  unsigned short* __restrict__ out,
                                                  int n4) {
  int i = blockIdx.x * 256 + threadIdx.x;
  if (i >= n4) return;
  float4 v = ((const float4*)in)[i];
  short4v o;
  o[0] = (short)f2bf(v.x); o[1] = (short)f2bf(v.y);
  o[2] = (short)f2bf(v.z); o[3] = (short)f2bf(v.w);
  ((short4v*)out)[i] = o;
}

// ------- GEMM C[M,N] = A[M,K] * B[N,K]^T, 128x256 tile, 4-phase + counted vmcnt -------
// The T3+T4 combo (phases AND counted waits together -- r3 had phases+drain0,
// r4 had counted+no-phases; m218: the gain requires both).
// 512 thr = 8 waves (2M x 4N), wave tile 64x64 = acc[4][4]. BK=64 (2 k-halves).
// LDS: 3-buffer ring x (A 128x64 + B 256x64) bf16 = 144 KB, 1 block/CU.
// Per K-tile: 4 phases {ds_read (6 or 2 b128) || stage 2 gloads(t+2) -> barrier
// -> 8 MFMA -> barrier}; tile-end s_waitcnt vmcnt(6): t+1 certified landed,
// t+2's 6 loads stay in flight across barriers. Drain only in peeled tail.
// Swizzle: 128B rows = 8 x 16B chunks, pos = c ^ (row&7) (full 8-position span,
// r6 lesson); inverse on global source, linear DMA dest, forward on ds_read.
// Grids quantize exactly: QKV 32x24=768=3.0x256CU, out-proj 32x8=256=1.0.
template<int F32OUT>
__global__ __launch_bounds__(512, 2) void gemm_8p_kernel(
    const bf16_t* __restrict__ A, const bf16_t* __restrict__ Bm,
    float* __restrict__ Cf, unsigned short* __restrict__ Cb,
    int M, int N, int K, int nbn) {
  __shared__ bf16_t lds[73728];   // 3 x (8192 A + 16384 B) elems = 144 KB
  const int tid = threadIdx.x;
  const int w = tid >> 6, lane = tid & 63;
  const int wm = w >> 2, wn = w & 3;
  const int l15 = lane & 15, g = lane >> 4;

  // XCD-bijective swizzle (grid % 8 == 0 in all launches here)
  const int nwg = gridDim.x;
  const int cpx = nwg >> 3;
  const int wg = (blockIdx.x & 7) * cpx + (blockIdx.x >> 3);
  const int bm0 = (wg / nbn) * 128, bn0 = (wg % nbn) * 256;

  // staging: one gload call = 512 thr x 16B = 64 rows x 128B. thread -> row
  // tid>>3, position tid&7 which holds global chunk (tid&7)^(row&7).
  const int srow = tid >> 3;
  const int sgc = (tid & 7) ^ (srow & 7);
  const bf16_t* agA = A + (size_t)(bm0 + srow) * K + sgc * 8;
  const bf16_t* agB = Bm + (size_t)(bn0 + srow) * K + sgc * 8;

#define STG_A(T) do { const int _s = (T) % 3;                                 \
    bf16_t* _d = lds + _s * 24576 + w * 512;                                  \
    async16(agA + (size_t)(T) * 64, _d);                                      \
    async16(agA + 64 * (size_t)K + (size_t)(T) * 64, _d + 4096); } while (0)
#define STG_B01(T) do { const int _s = (T) % 3;                               \
    bf16_t* _d = lds + _s * 24576 + 8192 + w * 512;                           \
    async16(agB + (size_t)(T) * 64, _d);                                      \
    async16(agB + 64 * (size_t)K + (size_t)(T) * 64, _d + 4096); } while (0)
#define STG_B23(T) do { const int _s = (T) % 3;                               \
    bf16_t* _d = lds + _s * 24576 + 8192 + w * 512;                           \
    async16(agB + 128 * (size_t)K + (size_t)(T) * 64, _d + 8192);             \
    async16(agB + 192 * (size_t)K + (size_t)(T) * 64, _d + 12288); } while (0)

  // ds_read: row r, k-chunk c=kk*4+g at position (c ^ (r&7))
  const int rdsw = l15 & 7;
  const int cof0 = ((g) ^ rdsw) * 8;        // kk=0
  const int cof1 = ((4 + g) ^ rdsw) * 8;    // kk=1

  f32x4 acc[4][4];
#pragma unroll
  for (int i = 0; i < 4; ++i)
#pragma unroll
    for (int j = 0; j < 4; ++j)
#pragma unroll
      for (int e = 0; e < 4; ++e) acc[i][j][e] = 0.0f;

#define MFMA_HALF(NLO, AF, B0, B1)                                            \
    _Pragma("unroll")                                                         \
    for (int mi = 0; mi < 4; ++mi) {                                          \
      acc[mi][NLO] = __builtin_amdgcn_mfma_f32_16x16x32_bf16(AF[mi], B0, acc[mi][NLO], 0, 0, 0); \
      acc[mi][NLO + 1] = __builtin_amdgcn_mfma_f32_16x16x32_bf16(AF[mi], B1, acc[mi][NLO + 1], 0, 0, 0); \
    }

#define TILE8(T, DOSTG, WNSTR, DOWAIT) do {                                   \
    const int _sb = (T) % 3;                                                  \
    const bf16_t* Ab = lds + _sb * 24576 + (wm * 64 + l15) * 64;              \
    const bf16_t* Bb = lds + _sb * 24576 + 8192 + (wn * 64 + l15) * 64;       \
    short8 af[4], b0, b1;                                                     \
    /* phase 0: A(kk0), B01(kk0) || stage A(t+2) */                           \
    _Pragma("unroll")                                                         \
    for (int mi = 0; mi < 4; ++mi) af[mi] = *(const short8*)(Ab + mi * 1024 + cof0); \
    b0 = *(const short8*)(Bb + cof0);                                         \
    b1 = *(const short8*)(Bb + 1024 + cof0);                                  \
    if (DOSTG) STG_A((T) + 2);                                                \
    __builtin_amdgcn_s_barrier();                                             \
    __builtin_amdgcn_s_setprio(1);                                            \
    MFMA_HALF(0, af, b0, b1);                                                 \
    __builtin_amdgcn_s_setprio(0);                                            \
    __builtin_amdgcn_s_barrier();                                             \
    /* phase 1: B23(kk0) || stage B01(t+2) */                                 \
    b0 = *(const short8*)(Bb + 2048 + cof0);                                  \
    b1 = *(const short8*)(Bb + 3072 + cof0);                                  \
    if (DOSTG) STG_B01((T) + 2);                                              \
    __builtin_amdgcn_s_barrier();                                             \
    __builtin_amdgcn_s_setprio(1);                                            \
    MFMA_HALF(2, af, b0, b1);                                                 \
    __builtin_amdgcn_s_setprio(0);                                            \
    __builtin_amdgcn_s_barrier();                                             \
    /* phase 2: A(kk1), B01(kk1) || stage B23(t+2) */                         \
    _Pragma("unroll")                                                         \
    for (int mi = 0; mi < 4; ++mi) af[mi] = *(const short8*)(Ab + mi * 1024 + cof1); \
    b0 = *(const short8*)(Bb + cof1);                                         \
    b1 = *(const short8*)(Bb + 1024 + cof1);                                  \
    if (DOSTG) STG_B23((T) + 2);                                              \
    __builtin_amdgcn_s_barrier();                                             \
    __builtin_amdgcn_s_setprio(1);                                            \
    MFMA_HALF(0, af, b0, b1);                                                 \
    __builtin_amdgcn_s_setprio(0);                                            \
    __builtin_amdgcn_s_barrier();                                             \
    /* phase 3: B23(kk1); tile-end counted wait */                            \
    b0 = *(const short8*)(Bb + 2048 + cof1);                                  \
    b1 = *(const short8*)(Bb + 3072 + cof1);                                  \
    __builtin_amdgcn_s_barrier();                                             \
    __builtin_amdgcn_s_setprio(1);                                            \
    MFMA_HALF(2, af, b0, b1);                                                 \
    __builtin_amdgcn_s_setprio(0);                                            \
    if (DOWAIT) asm volatile("s_waitcnt vmcnt(" WNSTR ")" ::: "memory");      \
    __builtin_amdgcn_s_barrier();                                             \
  } while (0)

  // prologue: tiles 0 and 1 staged; certify tile 0 (oldest 6), keep 6 in flight
  STG_A(0); STG_B01(0); STG_B23(0);
  STG_A(1); STG_B01(1); STG_B23(1);
  asm volatile("s_waitcnt vmcnt(6)" ::: "memory");
  __builtin_amdgcn_s_barrier();

  const int NT = K >> 6;   // 32
  for (int t = 0; t < NT - 2; ++t) TILE8(t, true, "6", true);
  TILE8(NT - 2, false, "0", true);
  TILE8(NT - 1, false, "0", false);
#undef TILE8
#undef MFMA_HALF
#undef STG_A
#undef STG_B01
#undef STG_B23

  // ---- epilogue ----
#pragma unroll
  for (int mi = 0; mi < 4; ++mi)
#pragma unroll
    for (int ni = 0; ni < 4; ++ni)
#pragma unroll
      for (int r = 0; r < 4; ++r) {
        int mr = bm0 + wm * 64 + mi * 16 + g * 4 + r;
        int nc = bn0 + wn * 64 + ni * 16 + l15;
        if (F32OUT)
          Cf[(size_t)mr * N + nc] = acc[mi][ni][r];
        else
          Cb[(size_t)mr * N + nc] = f2bf(acc[mi][ni][r]);
      }
}

// ---------------- RoPE + split + V transpose ----------------
__global__ __launch_bounds__(256) void rope_kernel(
    const bf16_t* __restrict__ qkv,
    const float* __restrict__ cosb, const float* __restrict__ sinb,
    bf16_t* __restrict__ qo, bf16_t* __restrict__ ko, bf16_t* __restrict__ vT) {
  const int nTT = T_SEQ / 64;
  const int bx = blockIdx.x;
  const int bh = bx / nTT, tt = bx % nTT;
  const int b = bh / N_HEADS, h = bh % N_HEADS;
  const int tid = threadIdx.x;
  __shared__ bf16_t vlds[64][136];

  const float SC = 0.08838834764831845f;  // 1/sqrt(128)

#pragma unroll
  for (int it = 0; it < 2; ++it) {
    int item = it * 256 + tid;
    int r = item >> 3, cg = item & 7;
    int t = tt * 64 + r;
    int c0 = cg * 8;
    size_t base = ((size_t)b * T_SEQ + t) * (size_t)(3 * D_MODEL) + (size_t)h * HEAD_DIM;

    float cs0[8], sn0[8], cs1[8], sn1[8];
    {
      const float* cp = cosb + (size_t)t * HEAD_DIM + c0;
      const float* sp = sinb + (size_t)t * HEAD_DIM + c0;
      float4 a0 = *(const float4*)(cp), a1 = *(const float4*)(cp + 4);
      float4 b0 = *(const float4*)(cp + 64), b1 = *(const float4*)(cp + 68);
      float4 s0 = *(const float4*)(sp), s1 = *(const float4*)(sp + 4);
      float4 t0 = *(const float4*)(sp + 64), t1 = *(const float4*)(sp + 68);
      cs0[0]=a0.x; cs0[1]=a0.y; cs0[2]=a0.z; cs0[3]=a0.w; cs0[4]=a1.x; cs0[5]=a1.y; cs0[6]=a1.z; cs0[7]=a1.w;
      cs1[0]=b0.x; cs1[1]=b0.y; cs1[2]=b0.z; cs1[3]=b0.w; cs1[4]=b1.x; cs1[5]=b1.y; cs1[6]=b1.z; cs1[7]=b1.w;
      sn0[0]=s0.x; sn0[1]=s0.y; sn0[2]=s0.z; sn0[3]=s0.w; sn0[4]=s1.x; sn0[5]=s1.y; sn0[6]=s1.z; sn0[7]=s1.w;
      sn1[0]=t0.x; sn1[1]=t0.y; sn1[2]=t0.z; sn1[3]=t0.w; sn1[4]=t1.x; sn1[5]=t1.y; sn1[6]=t1.z; sn1[7]=t1.w;
    }

#pragma unroll
    for (int sec = 0; sec < 2; ++sec) {
      size_t sbase = base + (size_t)sec * D_MODEL;
      short8 lo = *(const short8*)(qkv + sbase + c0);
      short8 hi = *(const short8*)(qkv + sbase + 64 + c0);
      short8 olo, ohi;
#pragma unroll
      for (int e = 0; e < 8; ++e) {
        float xl = bf2f(lo[e]), xh = bf2f(hi[e]);
        float rl = xl * cs0[e] - xh * sn0[e];
        float rh = xh * cs1[e] + xl * sn1[e];
        if (sec == 0) { rl *= SC; rh *= SC; }
        olo[e] = (short)f2bf(rl);
        ohi[e] = (short)f2bf(rh);
      }
      bf16_t* dst = (sec == 0 ? qo : ko) + ((size_t)bh * T_SEQ + t) * HEAD_DIM + c0;
      *(short8*)dst = olo;
      *(short8*)(dst + 64) = ohi;
    }

    short8 v0 = *(const short8*)(qkv + base + 2 * D_MODEL + c0);
    short8 v1 = *(const short8*)(qkv + base + 2 * D_MODEL + 64 + c0);
    *(short8*)&vlds[r][c0] = v0;
    *(short8*)&vlds[r][64 + c0] = v1;
  }
  __syncthreads();

  int hd = tid >> 1, hf = tid & 1;
  bf16_t* dst = vT + ((size_t)bh * HEAD_DIM + hd) * T_SEQ + tt * 64 + hf * 32;
#pragma unroll
  for (int jj = 0; jj < 4; ++jj) {
    short8 o;
#pragma unroll
    for (int e = 0; e < 8; ++e)
      o[e] = *(const short*)&vlds[hf * 32 + jj * 8 + e][hd];
    *(short8*)(dst + jj * 8) = o;
  }
}

// ---------------- causal flash attention: swapped-QK^T 32x32, in-reg softmax ----
// (round-12 kernel verbatim -- passed, attn ~85 us)
__global__ __launch_bounds__(256, 2) void attn_kernel(
    const bf16_t* __restrict__ q, const bf16_t* __restrict__ k,
    const bf16_t* __restrict__ vT, unsigned short* __restrict__ attn) {
  const int bx = blockIdx.x;
  const int bh = bx & 31;
  const int qi = (bx >> 5) & 7;
  const int qt = (bx >> 8) ? qi : 15 - qi;
  const int b = bh / N_HEADS, h = bh % N_HEADS;
  const int tid = threadIdx.x;
  const int w = tid >> 6, lane = tid & 63;
  const int l31 = lane & 31, hi = lane >> 5;
  const int swz = l31 & 7;
  const float LOG2E = 1.44269504088896340736f;

  __shared__ bf16_t smem[32768];

  const bf16_t* qb = q + (size_t)bh * T_SEQ * HEAD_DIM;
  const bf16_t* kb = k + (size_t)bh * T_SEQ * HEAD_DIM;
  const bf16_t* vb = vT + (size_t)bh * HEAD_DIM * T_SEQ;

  const int qlo = qt * 128 + w * 32;
  const int qhi = qlo + 31;
  const int qrow = qlo + l31;

  short8 qf[8];
#pragma unroll
  for (int ks = 0; ks < 8; ++ks)
    qf[ks] = *(const short8*)(qb + (size_t)qrow * HEAD_DIM + ks * 16 + hi * 8);

  float m = -3.0e38f, l = 0.0f;
  f32x16 O[4];
#pragma unroll
  for (int dt = 0; dt < 4; ++dt)
#pragma unroll
    for (int r = 0; r < 16; ++r) O[dt][r] = 0.0f;

#define STAGE_TILES(KT, BU) {                                                    \
    _Pragma("unroll")                                                            \
    for (int j = 0; j < 4; ++j) {                                                \
      int s = j * 4 + w;                                                         \
      int row = s * 4 + (lane >> 4);                                             \
      int gc = (lane & 15) ^ (row & 7);                                          \
      async16(kb + (size_t)((KT) * 64 + row) * HEAD_DIM + gc * 8,                \
              smem + (BU) * 8192 + s * 512);                                     \
    }                                                                            \
    _Pragma("unroll")                                                            \
    for (int j = 0; j < 4; ++j) {                                                \
      int s = j * 4 + w;                                                         \
      int row = s * 8 + (lane >> 3);                                             \
      int gc = (lane & 7) ^ (row & 7);                                           \
      async16(vb + (size_t)row * T_SEQ + (KT) * 64 + gc * 8,                     \
              smem + 16384 + (BU) * 8192 + s * 512);                             \
    }                                                                            \
  }

  STAGE_TILES(0, 0);
  __syncthreads();
  int buf = 0;

  const int lastk = 2 * qt + 1;
  for (int kt = 0; kt <= lastk; ++kt) {
    if (kt < lastk) STAGE_TILES(kt + 1, buf ^ 1);
    const bf16_t* Ks = smem + buf * 8192;
    const bf16_t* Vs = smem + 16384 + buf * 8192;
    const bool active = (kt * 64 <= qhi);

    if (active) {
      f32x16 S[2];
#pragma unroll
      for (int kvt = 0; kvt < 2; ++kvt) {
        const int kvbase = kt * 64 + kvt * 32;
        if (kvbase <= qhi) {
          const int krow = kvt * 32 + l31;
#pragma unroll
          for (int r = 0; r < 16; ++r) S[kvt][r] = 0.0f;
          __builtin_amdgcn_s_setprio(1);
#pragma unroll
          for (int ks = 0; ks < 8; ++ks) {
            int c = (2 * ks + hi) ^ swz;
            short8 kf = *(const short8*)(Ks + krow * 128 + c * 8);
            S[kvt] = __builtin_amdgcn_mfma_f32_32x32x16_bf16(kf, qf[ks], S[kvt], 0, 0, 0);
          }
          __builtin_amdgcn_s_setprio(0);
          if (kvbase + 31 > qlo) {
#pragma unroll
            for (int r = 0; r < 16; ++r) {
              int kv = kvbase + (r & 3) + 8 * (r >> 2) + 4 * hi;
              if (kv > qrow) S[kvt][r] = -3.0e38f;
            }
          }
        } else {
#pragma unroll
          for (int r = 0; r < 16; ++r) S[kvt][r] = -3.0e38f;
        }
      }

      float rl = -3.0e38f;
#pragma unroll
      for (int kvt = 0; kvt < 2; ++kvt)
#pragma unroll
        for (int r = 0; r < 16; ++r) rl = fmaxf(rl, S[kvt][r]);
      rl = fmaxf(rl, __shfl_xor(rl, 32, 64));
      float mn = fmaxf(m, rl);
      float fac = exp2f((m - mn) * LOG2E);
      m = mn;
      float sum = 0.0f;
#pragma unroll
      for (int kvt = 0; kvt < 2; ++kvt)
#pragma unroll
        for (int r = 0; r < 16; ++r) {
          float p = exp2f((S[kvt][r] - m) * LOG2E);
          S[kvt][r] = p;
          sum += p;
        }
      sum += __shfl_xor(sum, 32, 64);
      l = l * fac + sum;
#pragma unroll
      for (int dt = 0; dt < 4; ++dt)
#pragma unroll
        for (int r = 0; r < 16; ++r) O[dt][r] *= fac;

      short8 pf[4];
#pragma unroll
      for (int ks = 0; ks < 4; ++ks) {
        const int kvt = ks >> 1;
        const int base = (ks & 1) * 8;
        unsigned pkL0, pkL1, pkH0, pkH1;
        {
          float a0 = S[kvt][base + 0], a1 = S[kvt][base + 1];
          float a2 = S[kvt][base + 2], a3 = S[kvt][base + 3];
          float b0 = S[kvt][base + 4], b1 = S[kvt][base + 5];
          float b2 = S[kvt][base + 6], b3 = S[kvt][base + 7];
          asm("v_cvt_pk_bf16_f32 %0, %1, %2" : "=v"(pkL0) : "v"(a0), "v"(a1));
          asm("v_cvt_pk_bf16_f32 %0, %1, %2" : "=v"(pkL1) : "v"(a2), "v"(a3));
          asm("v_cvt_pk_bf16_f32 %0, %1, %2" : "=v"(pkH0) : "v"(b0), "v"(b1));
          asm("v_cvt_pk_bf16_f32 %0, %1, %2" : "=v"(pkH1) : "v"(b2), "v"(b3));
        }
        unsigned sx0 = hi ? pkL0 : pkH0;
        unsigned sx1 = hi ? pkL1 : pkH1;
        unsigned rx0 = (unsigned)__shfl_xor((int)sx0, 32, 64);
        unsigned rx1 = (unsigned)__shfl_xor((int)sx1, 32, 64);
        union { unsigned u[4]; short8 s; } uu;
        uu.u[0] = hi ? rx0 : pkL0;
        uu.u[1] = hi ? rx1 : pkL1;
        uu.u[2] = hi ? pkH0 : rx0;
        uu.u[3] = hi ? pkH1 : rx1;
        pf[ks] = uu.s;
      }

      __builtin_amdgcn_s_setprio(1);
#pragma unroll
      for (int dt = 0; dt < 4; ++dt) {
        const int vrow = dt * 32 + l31;
#pragma unroll
        for (int ks = 0; ks < 4; ++ks) {
          int c = (2 * ks + hi) ^ swz;
          short8 vf = *(const short8*)(Vs + vrow * 64 + c * 8);
          O[dt] = __builtin_amdgcn_mfma_f32_32x32x16_bf16(vf, pf[ks], O[dt], 0, 0, 0);
        }
      }
      __builtin_amdgcn_s_setprio(0);
    }

    __syncthreads();
    buf ^= 1;
  }
#undef STAGE_TILES

  float inv = 1.0f / l;
  bf16_t* ol = smem + w * 4352;
#pragma unroll
  for (int dt = 0; dt < 4; ++dt)
#pragma unroll
    for (int r = 0; r < 16; ++r) {
      int d = dt * 32 + (r & 3) + 8 * (r >> 2) + 4 * hi;
      *(unsigned short*)&ol[l31 * 136 + d] = f2bf(O[dt][r] * inv);
    }
  __syncthreads();
  const int srow4 = lane >> 4;
  const int scol = (lane & 15) * 8;
#pragma unroll
  for (int rr = 0; rr < 8; ++rr) {
    int row = rr * 4 + srow4;
    short8 v = *(const short8*)(ol + row * 136 + scol);
    *(short8*)(attn + ((size_t)b * T_SEQ + qt * 128 + w * 32 + row) * D_MODEL +
               (size_t)h * HEAD_DIM + scol) = v;
  }
}

// ---------------- launch ----------------
extern "C" void kernel_launch(void* const* d_in, const int* in_sizes, int n_in,
                              void* d_out, int out_size, void* d_ws, size_t ws_size,
                              hipStream_t stream) {
  const float* x    = (const float*)d_in[0];
  const float* cosb = (const float*)d_in[1];
  const float* sinb = (const float*)d_in[2];
  const float* Wqkv = (const float*)d_in[3];
  const float* Wout = (const float*)d_in[4];
  float* out = (float*)d_out;

  char* ws = (char*)d_ws;
  size_t off = 0;
  bf16_t* xb    = (bf16_t*)(ws + off); off += (size_t)4096 * 2048 * 2;
  bf16_t* wqkvb = (bf16_t*)(ws + off); off += (size_t)6144 * 2048 * 2;
  bf16_t* woutb = (bf16_t*)(ws + off); off += (size_t)2048 * 2048 * 2;
  bf16_t* qkvb  = (bf16_t*)(ws + off); off += (size_t)4096 * 6144 * 2;
  bf16_t* qb    = (bf16_t*)(ws + off); off += (size_t)32 * 2048 * 128 * 2;
  bf16_t* kb    = (bf16_t*)(ws + off); off += (size_t)32 * 2048 * 128 * 2;
  bf16_t* vTb   = (bf16_t*)(ws + off); off += (size_t)32 * 2048 * 128 * 2;
  bf16_t* attnb = xb;  // xb dead after QKV GEMM

  cvt_kernel<<<8192, 256, 0, stream>>>(x, (unsigned short*)xb, 4096 * 2048 / 4);
  cvt_kernel<<<12288, 256, 0, stream>>>(Wqkv, (unsigned short*)wqkvb, 6144 * 2048 / 4);
  cvt_kernel<<<4096, 256, 0, stream>>>(Wout, (unsigned short*)woutb, 2048 * 2048 / 4);

  // QKV: M=4096, N=6144 -> 32x24 = 768 blocks = 3.0 x 256 CUs exact
  gemm_8p_kernel<0><<<768, 512, 0, stream>>>(xb, wqkvb, nullptr, (unsigned short*)qkvb,
                                             4096, 6144, 2048, 24);

  rope_kernel<<<1024, 256, 0, stream>>>(qkvb, cosb, sinb, qb, kb, vTb);

  // 512 blocks: 32 bh x 16 q-tiles of 128 rows; 2 blocks/CU, paired workloads
  attn_kernel<<<512, 256, 0, stream>>>(qb, kb, vTb, (unsigned short*)attnb);

  // out-proj: M=4096, N=2048 -> 32x8 = 256 blocks = 1.0 x 256 CUs exact
  gemm_8p_kernel<1><<<256, 512, 0, stream>>>(attnb, woutb, out, nullptr,
                                             4096, 2048, 2048, 8);
}

// Round 14
// 263.620 us; speedup vs baseline: 1.0560x; 1.0560x over previous
//
#include <hip/hip_runtime.h>
#include <hip/hip_bf16.h>
#include <stdint.h>

#define T_SEQ 2048
#define D_MODEL 2048
#define N_HEADS 16
#define HEAD_DIM 128

typedef __hip_bfloat16 bf16_t;
typedef __attribute__((ext_vector_type(8))) short short8;
typedef __attribute__((ext_vector_type(4))) short short4v;
typedef __attribute__((ext_vector_type(4))) float f32x4;
typedef __attribute__((ext_vector_type(16))) float f32x16;

__device__ __forceinline__ unsigned short f2bf(float x) {
  union { float f; unsigned u; } c; c.f = x;
  unsigned u = c.u;
  u += 0x7fffu + ((u >> 16) & 1u);   // RNE
  return (unsigned short)(u >> 16);
}
__device__ __forceinline__ float bf2f(short v) {
  union { unsigned u; float f; } c;
  c.u = ((unsigned)(unsigned short)v) << 16;
  return c.f;
}
__device__ __forceinline__ void async16(const bf16_t* g, bf16_t* l) {
  __builtin_amdgcn_global_load_lds(
      (const __attribute__((address_space(1))) void*)g,
      (__attribute__((address_space(3))) void*)l, 16, 0, 0);
}

// ---------------- fused f32 -> bf16 conversion (x, Wqkv, Wout in one launch) ----------------
__global__ __launch_bounds__(256) void cvt3_kernel(
    const float* __restrict__ x, const float* __restrict__ wqkv,
    const float* __restrict__ wout,
    unsigned short* __restrict__ xb, unsigned short* __restrict__ wqkvb,
    unsigned short* __restrict__ woutb) {
  const int N1 = 4096 * 2048 / 4;          // 2,097,152
  const int N2 = 6144 * 2048 / 4;          // 3,145,728
  const int N3 = 2048 * 2048 / 4;          // 1,048,576
  const int total = N1 + N2 + N3;
  for (int i = blockIdx.x * 256 + threadIdx.x; i < total; i += gridDim.x * 256) {
    const float* src; unsigned short* dst; int j;
    if (i < N1)            { src = x;    dst = xb;    j = i; }
    else if (i < N1 + N2)  { src = wqkv; dst = wqkvb; j = i - N1; }
    else                   { src = wout; dst = woutb; j = i - N1 - N2; }
    float4 v = ((const float4*)src)[j];
    short4v o;
    o[0] = (short)f2bf(v.x); o[1] = (short)f2bf(v.y);
    o[2] = (short)f2bf(v.z); o[3] = (short)f2bf(v.w);
    ((short4v*)dst)[j] = o;
  }
}

// ---------------- GEMM C[M,N] = A[M,K] * B[N,K]^T, 128x256 tile ----------------
// Round-5 kernel verbatim (measured: 115 us QKV, 0 bank conflicts, 2 blocks/CU).
// GEMM structure ceiling declared (r3/r4/r6/r13 all failed to beat this).
template<int F32OUT>
__global__ __launch_bounds__(512, 4) void gemm_tp_kernel(
    const bf16_t* __restrict__ A, const bf16_t* __restrict__ Bm,
    float* __restrict__ Cf, unsigned short* __restrict__ Cb,
    int M, int N, int K, int nbn) {
  __shared__ bf16_t lds[36864];   // 3 x 12288 elems = 72 KB
  const int tid = threadIdx.x;
  const int w = tid >> 6, lane = tid & 63;
  const int wm = w >> 2, wn = w & 3;
  const int l15 = lane & 15, g = lane >> 4;

  const int nwg = gridDim.x;
  const int cpx = nwg >> 3;
  const int wg = (blockIdx.x & 7) * cpx + (blockIdx.x >> 3);
  const int bm0 = (wg / nbn) * 128, bn0 = (wg % nbn) * 256;

  const int sl = tid >> 3;
  const int su = (tid & 7) ^ (sl & 7);
  const int srow = (sl << 1) | (su >> 2);
  const int sc8 = su & 3;
  const bf16_t* agA = A + (size_t)(bm0 + srow) * K + sc8 * 8;
  const bf16_t* agB = Bm + (size_t)(bn0 + srow) * K + sc8 * 8;

#define STAGE(KT, SB) do {                                                    \
    bf16_t* _d = lds + (SB) * 12288 + w * 512;                                \
    async16(agA + (size_t)(KT) * 32, _d);                                     \
    async16(agB + (size_t)(KT) * 32, _d + 4096);                              \
    async16(agB + 128 * (size_t)K + (size_t)(KT) * 32, _d + 8192);            \
  } while (0)

  const int lhalf = l15 >> 1;
  const int aoff = lhalf * 64 + (((((l15 & 1) << 2) | g) ^ lhalf)) * 8;
  const bf16_t* Abase = lds + wm * 2048 + aoff;
  const bf16_t* Bbase = lds + 4096 + wn * 2048 + aoff;

  f32x4 acc[4][4];
#pragma unroll
  for (int i = 0; i < 4; ++i)
#pragma unroll
    for (int j = 0; j < 4; ++j)
#pragma unroll
      for (int e = 0; e < 4; ++e) acc[i][j][e] = 0.0f;

  STAGE(0, 0);
  STAGE(1, 1);

  const int NT = K >> 5;
  int cb = 0, sb = 2;
  for (int kt = 0; kt < NT - 1; ++kt) {
    asm volatile("s_waitcnt vmcnt(3)" ::: "memory");
    __builtin_amdgcn_s_barrier();
    const bf16_t* Ab = Abase + cb * 12288;
    const bf16_t* Bb = Bbase + cb * 12288;
    short8 af[4], bfr[4];
#pragma unroll
    for (int mi = 0; mi < 4; ++mi) af[mi] = *(const short8*)(Ab + mi * 512);
#pragma unroll
    for (int ni = 0; ni < 4; ++ni) bfr[ni] = *(const short8*)(Bb + ni * 512);
    if (kt < NT - 2) STAGE(kt + 2, sb);
    __builtin_amdgcn_s_setprio(1);
#pragma unroll
    for (int mi = 0; mi < 4; ++mi)
#pragma unroll
      for (int ni = 0; ni < 4; ++ni)
        acc[mi][ni] = __builtin_amdgcn_mfma_f32_16x16x32_bf16(
            af[mi], bfr[ni], acc[mi][ni], 0, 0, 0);
    __builtin_amdgcn_s_setprio(0);
    cb = (cb == 2) ? 0 : cb + 1;
    sb = (sb == 2) ? 0 : sb + 1;
  }
  {
    asm volatile("s_waitcnt vmcnt(0)" ::: "memory");
    __builtin_amdgcn_s_barrier();
    const bf16_t* Ab = Abase + cb * 12288;
    const bf16_t* Bb = Bbase + cb * 12288;
    short8 af[4], bfr[4];
#pragma unroll
    for (int mi = 0; mi < 4; ++mi) af[mi] = *(const short8*)(Ab + mi * 512);
#pragma unroll
    for (int ni = 0; ni < 4; ++ni) bfr[ni] = *(const short8*)(Bb + ni * 512);
    __builtin_amdgcn_s_setprio(1);
#pragma unroll
    for (int mi = 0; mi < 4; ++mi)
#pragma unroll
      for (int ni = 0; ni < 4; ++ni)
        acc[mi][ni] = __builtin_amdgcn_mfma_f32_16x16x32_bf16(
            af[mi], bfr[ni], acc[mi][ni], 0, 0, 0);
    __builtin_amdgcn_s_setprio(0);
  }
#undef STAGE

#pragma unroll
  for (int mi = 0; mi < 4; ++mi)
#pragma unroll
    for (int ni = 0; ni < 4; ++ni)
#pragma unroll
      for (int r = 0; r < 4; ++r) {
        int mr = bm0 + wm * 64 + mi * 16 + g * 4 + r;
        int nc = bn0 + wn * 64 + ni * 16 + l15;
        if (F32OUT)
          Cf[(size_t)mr * N + nc] = acc[mi][ni][r];
        else
          Cb[(size_t)mr * N + nc] = f2bf(acc[mi][ni][r]);
      }
}

// ---------------- RoPE + split + V transpose ----------------
__global__ __launch_bounds__(256) void rope_kernel(
    const bf16_t* __restrict__ qkv,
    const float* __restrict__ cosb, const float* __restrict__ sinb,
    bf16_t* __restrict__ qo, bf16_t* __restrict__ ko, bf16_t* __restrict__ vT) {
  const int nTT = T_SEQ / 64;
  const int bx = blockIdx.x;
  const int bh = bx / nTT, tt = bx % nTT;
  const int b = bh / N_HEADS, h = bh % N_HEADS;
  const int tid = threadIdx.x;
  __shared__ bf16_t vlds[64][136];

  const float SC = 0.08838834764831845f;  // 1/sqrt(128)

#pragma unroll
  for (int it = 0; it < 2; ++it) {
    int item = it * 256 + tid;
    int r = item >> 3, cg = item & 7;
    int t = tt * 64 + r;
    int c0 = cg * 8;
    size_t base = ((size_t)b * T_SEQ + t) * (size_t)(3 * D_MODEL) + (size_t)h * HEAD_DIM;

    float cs0[8], sn0[8], cs1[8], sn1[8];
    {
      const float* cp = cosb + (size_t)t * HEAD_DIM + c0;
      const float* sp = sinb + (size_t)t * HEAD_DIM + c0;
      float4 a0 = *(const float4*)(cp), a1 = *(const float4*)(cp + 4);
      float4 b0 = *(const float4*)(cp + 64), b1 = *(const float4*)(cp + 68);
      float4 s0 = *(const float4*)(sp), s1 = *(const float4*)(sp + 4);
      float4 t0 = *(const float4*)(sp + 64), t1 = *(const float4*)(sp + 68);
      cs0[0]=a0.x; cs0[1]=a0.y; cs0[2]=a0.z; cs0[3]=a0.w; cs0[4]=a1.x; cs0[5]=a1.y; cs0[6]=a1.z; cs0[7]=a1.w;
      cs1[0]=b0.x; cs1[1]=b0.y; cs1[2]=b0.z; cs1[3]=b0.w; cs1[4]=b1.x; cs1[5]=b1.y; cs1[6]=b1.z; cs1[7]=b1.w;
      sn0[0]=s0.x; sn0[1]=s0.y; sn0[2]=s0.z; sn0[3]=s0.w; sn0[4]=s1.x; sn0[5]=s1.y; sn0[6]=s1.z; sn0[7]=s1.w;
      sn1[0]=t0.x; sn1[1]=t0.y; sn1[2]=t0.z; sn1[3]=t0.w; sn1[4]=t1.x; sn1[5]=t1.y; sn1[6]=t1.z; sn1[7]=t1.w;
    }

#pragma unroll
    for (int sec = 0; sec < 2; ++sec) {
      size_t sbase = base + (size_t)sec * D_MODEL;
      short8 lo = *(const short8*)(qkv + sbase + c0);
      short8 hi = *(const short8*)(qkv + sbase + 64 + c0);
      short8 olo, ohi;
#pragma unroll
      for (int e = 0; e < 8; ++e) {
        float xl = bf2f(lo[e]), xh = bf2f(hi[e]);
        float rl = xl * cs0[e] - xh * sn0[e];
        float rh = xh * cs1[e] + xl * sn1[e];
        if (sec == 0) { rl *= SC; rh *= SC; }
        olo[e] = (short)f2bf(rl);
        ohi[e] = (short)f2bf(rh);
      }
      bf16_t* dst = (sec == 0 ? qo : ko) + ((size_t)bh * T_SEQ + t) * HEAD_DIM + c0;
      *(short8*)dst = olo;
      *(short8*)(dst + 64) = ohi;
    }

    short8 v0 = *(const short8*)(qkv + base + 2 * D_MODEL + c0);
    short8 v1 = *(const short8*)(qkv + base + 2 * D_MODEL + 64 + c0);
    *(short8*)&vlds[r][c0] = v0;
    *(short8*)&vlds[r][64 + c0] = v1;
  }
  __syncthreads();

  int hd = tid >> 1, hf = tid & 1;
  bf16_t* dst = vT + ((size_t)bh * HEAD_DIM + hd) * T_SEQ + tt * 64 + hf * 32;
#pragma unroll
  for (int jj = 0; jj < 4; ++jj) {
    short8 o;
#pragma unroll
    for (int e = 0; e < 8; ++e)
      o[e] = *(const short*)&vlds[hf * 32 + jj * 8 + e][hd];
    *(short8*)(dst + jj * 8) = o;
  }
}

// ---------------- causal flash attention: swapped-QK^T 32x32, in-reg softmax ----
// (round-12 structure + T13 defer-max: skip O-rescale when __all(rl <= m+8);
// wave-uniform branch, P bounded by e^8 -- safe in f32 accumulation.)
__global__ __launch_bounds__(256, 2) void attn_kernel(
    const bf16_t* __restrict__ q, const bf16_t* __restrict__ k,
    const bf16_t* __restrict__ vT, unsigned short* __restrict__ attn) {
  const int bx = blockIdx.x;
  const int bh = bx & 31;
  const int qi = (bx >> 5) & 7;
  const int qt = (bx >> 8) ? qi : 15 - qi;
  const int b = bh / N_HEADS, h = bh % N_HEADS;
  const int tid = threadIdx.x;
  const int w = tid >> 6, lane = tid & 63;
  const int l31 = lane & 31, hi = lane >> 5;
  const int swz = l31 & 7;
  const float LOG2E = 1.44269504088896340736f;

  __shared__ bf16_t smem[32768];

  const bf16_t* qb = q + (size_t)bh * T_SEQ * HEAD_DIM;
  const bf16_t* kb = k + (size_t)bh * T_SEQ * HEAD_DIM;
  const bf16_t* vb = vT + (size_t)bh * HEAD_DIM * T_SEQ;

  const int qlo = qt * 128 + w * 32;
  const int qhi = qlo + 31;
  const int qrow = qlo + l31;

  short8 qf[8];
#pragma unroll
  for (int ks = 0; ks < 8; ++ks)
    qf[ks] = *(const short8*)(qb + (size_t)qrow * HEAD_DIM + ks * 16 + hi * 8);

  float m = -3.0e38f, l = 0.0f;
  f32x16 O[4];
#pragma unroll
  for (int dt = 0; dt < 4; ++dt)
#pragma unroll
    for (int r = 0; r < 16; ++r) O[dt][r] = 0.0f;

#define STAGE_TILES(KT, BU) {                                                    \
    _Pragma("unroll")                                                            \
    for (int j = 0; j < 4; ++j) {                                                \
      int s = j * 4 + w;                                                         \
      int row = s * 4 + (lane >> 4);                                             \
      int gc = (lane & 15) ^ (row & 7);                                          \
      async16(kb + (size_t)((KT) * 64 + row) * HEAD_DIM + gc * 8,                \
              smem + (BU) * 8192 + s * 512);                                     \
    }                                                                            \
    _Pragma("unroll")                                                            \
    for (int j = 0; j < 4; ++j) {                                                \
      int s = j * 4 + w;                                                         \
      int row = s * 8 + (lane >> 3);                                             \
      int gc = (lane & 7) ^ (row & 7);                                           \
      async16(vb + (size_t)row * T_SEQ + (KT) * 64 + gc * 8,                     \
              smem + 16384 + (BU) * 8192 + s * 512);                             \
    }                                                                            \
  }

  STAGE_TILES(0, 0);
  __syncthreads();
  int buf = 0;

  const int lastk = 2 * qt + 1;
  for (int kt = 0; kt <= lastk; ++kt) {
    if (kt < lastk) STAGE_TILES(kt + 1, buf ^ 1);
    const bf16_t* Ks = smem + buf * 8192;
    const bf16_t* Vs = smem + 16384 + buf * 8192;
    const bool active = (kt * 64 <= qhi);

    if (active) {
      f32x16 S[2];
#pragma unroll
      for (int kvt = 0; kvt < 2; ++kvt) {
        const int kvbase = kt * 64 + kvt * 32;
        if (kvbase <= qhi) {
          const int krow = kvt * 32 + l31;
#pragma unroll
          for (int r = 0; r < 16; ++r) S[kvt][r] = 0.0f;
          __builtin_amdgcn_s_setprio(1);
#pragma unroll
          for (int ks = 0; ks < 8; ++ks) {
            int c = (2 * ks + hi) ^ swz;
            short8 kf = *(const short8*)(Ks + krow * 128 + c * 8);
            S[kvt] = __builtin_amdgcn_mfma_f32_32x32x16_bf16(kf, qf[ks], S[kvt], 0, 0, 0);
          }
          __builtin_amdgcn_s_setprio(0);
          if (kvbase + 31 > qlo) {
#pragma unroll
            for (int r = 0; r < 16; ++r) {
              int kv = kvbase + (r & 3) + 8 * (r >> 2) + 4 * hi;
              if (kv > qrow) S[kvt][r] = -3.0e38f;
            }
          }
        } else {
#pragma unroll
          for (int r = 0; r < 16; ++r) S[kvt][r] = -3.0e38f;
        }
      }

      // ---- in-register online softmax with defer-max (T13) ----
      float rl = -3.0e38f;
#pragma unroll
      for (int kvt = 0; kvt < 2; ++kvt)
#pragma unroll
        for (int r = 0; r < 16; ++r) rl = fmaxf(rl, S[kvt][r]);
      rl = fmaxf(rl, __shfl_xor(rl, 32, 64));
      const bool defer = __all(rl <= m + 8.0f) != 0;   // wave-uniform
      if (!defer) {
        float mn = fmaxf(m, rl);
        float fac = exp2f((m - mn) * LOG2E);
        m = mn;
        l *= fac;
#pragma unroll
        for (int dt = 0; dt < 4; ++dt)
#pragma unroll
          for (int r = 0; r < 16; ++r) O[dt][r] *= fac;
      }
      float sum = 0.0f;
#pragma unroll
      for (int kvt = 0; kvt < 2; ++kvt)
#pragma unroll
        for (int r = 0; r < 16; ++r) {
          float p = exp2f((S[kvt][r] - m) * LOG2E);
          S[kvt][r] = p;
          sum += p;
        }
      sum += __shfl_xor(sum, 32, 64);
      l += sum;

      short8 pf[4];
#pragma unroll
      for (int ks = 0; ks < 4; ++ks) {
        const int kvt = ks >> 1;
        const int base = (ks & 1) * 8;
        unsigned pkL0, pkL1, pkH0, pkH1;
        {
          float a0 = S[kvt][base + 0], a1 = S[kvt][base + 1];
          float a2 = S[kvt][base + 2], a3 = S[kvt][base + 3];
          float b0 = S[kvt][base + 4], b1 = S[kvt][base + 5];
          float b2 = S[kvt][base + 6], b3 = S[kvt][base + 7];
          asm("v_cvt_pk_bf16_f32 %0, %1, %2" : "=v"(pkL0) : "v"(a0), "v"(a1));
          asm("v_cvt_pk_bf16_f32 %0, %1, %2" : "=v"(pkL1) : "v"(a2), "v"(a3));
          asm("v_cvt_pk_bf16_f32 %0, %1, %2" : "=v"(pkH0) : "v"(b0), "v"(b1));
          asm("v_cvt_pk_bf16_f32 %0, %1, %2" : "=v"(pkH1) : "v"(b2), "v"(b3));
        }
        unsigned sx0 = hi ? pkL0 : pkH0;
        unsigned sx1 = hi ? pkL1 : pkH1;
        unsigned rx0 = (unsigned)__shfl_xor((int)sx0, 32, 64);
        unsigned rx1 = (unsigned)__shfl_xor((int)sx1, 32, 64);
        union { unsigned u[4]; short8 s; } uu;
        uu.u[0] = hi ? rx0 : pkL0;
        uu.u[1] = hi ? rx1 : pkL1;
        uu.u[2] = hi ? pkH0 : rx0;
        uu.u[3] = hi ? pkH1 : rx1;
        pf[ks] = uu.s;
      }

      __builtin_amdgcn_s_setprio(1);
#pragma unroll
      for (int dt = 0; dt < 4; ++dt) {
        const int vrow = dt * 32 + l31;
#pragma unroll
        for (int ks = 0; ks < 4; ++ks) {
          int c = (2 * ks + hi) ^ swz;
          short8 vf = *(const short8*)(Vs + vrow * 64 + c * 8);
          O[dt] = __builtin_amdgcn_mfma_f32_32x32x16_bf16(vf, pf[ks], O[dt], 0, 0, 0);
        }
      }
      __builtin_amdgcn_s_setprio(0);
    }

    __syncthreads();
    buf ^= 1;
  }
#undef STAGE_TILES

  float inv = 1.0f / l;
  bf16_t* ol = smem + w * 4352;
#pragma unroll
  for (int dt = 0; dt < 4; ++dt)
#pragma unroll
    for (int r = 0; r < 16; ++r) {
      int d = dt * 32 + (r & 3) + 8 * (r >> 2) + 4 * hi;
      *(unsigned short*)&ol[l31 * 136 + d] = f2bf(O[dt][r] * inv);
    }
  __syncthreads();
  const int srow4 = lane >> 4;
  const int scol = (lane & 15) * 8;
#pragma unroll
  for (int rr = 0; rr < 8; ++rr) {
    int row = rr * 4 + srow4;
    short8 v = *(const short8*)(ol + row * 136 + scol);
    *(short8*)(attn + ((size_t)b * T_SEQ + qt * 128 + w * 32 + row) * D_MODEL +
               (size_t)h * HEAD_DIM + scol) = v;
  }
}

// ---------------- launch ----------------
extern "C" void kernel_launch(void* const* d_in, const int* in_sizes, int n_in,
                              void* d_out, int out_size, void* d_ws, size_t ws_size,
                              hipStream_t stream) {
  const float* x    = (const float*)d_in[0];
  const float* cosb = (const float*)d_in[1];
  const float* sinb = (const float*)d_in[2];
  const float* Wqkv = (const float*)d_in[3];
  const float* Wout = (const float*)d_in[4];
  float* out = (float*)d_out;

  char* ws = (char*)d_ws;
  size_t off = 0;
  bf16_t* xb    = (bf16_t*)(ws + off); off += (size_t)4096 * 2048 * 2;
  bf16_t* wqkvb = (bf16_t*)(ws + off); off += (size_t)6144 * 2048 * 2;
  bf16_t* woutb = (bf16_t*)(ws + off); off += (size_t)2048 * 2048 * 2;
  bf16_t* qkvb  = (bf16_t*)(ws + off); off += (size_t)4096 * 6144 * 2;
  bf16_t* qb    = (bf16_t*)(ws + off); off += (size_t)32 * 2048 * 128 * 2;
  bf16_t* kb    = (bf16_t*)(ws + off); off += (size_t)32 * 2048 * 128 * 2;
  bf16_t* vTb   = (bf16_t*)(ws + off); off += (size_t)32 * 2048 * 128 * 2;
  bf16_t* attnb = xb;  // xb dead after QKV GEMM

  cvt3_kernel<<<2048, 256, 0, stream>>>(x, Wqkv, Wout,
                                        (unsigned short*)xb, (unsigned short*)wqkvb,
                                        (unsigned short*)woutb);

  // QKV: M=4096, N=6144 -> 32x24 = 768 blocks
  gemm_tp_kernel<0><<<768, 512, 0, stream>>>(xb, wqkvb, nullptr, (unsigned short*)qkvb,
                                             4096, 6144, 2048, 24);

  rope_kernel<<<1024, 256, 0, stream>>>(qkvb, cosb, sinb, qb, kb, vTb);

  // 512 blocks: 32 bh x 16 q-tiles of 128 rows; 2 blocks/CU, paired workloads
  attn_kernel<<<512, 256, 0, stream>>>(qb, kb, vTb, (unsigned short*)attnb);

  // out-proj: M=4096, N=2048 -> 32x8 = 256 blocks
  gemm_tp_kernel<1><<<256, 512, 0, stream>>>(attnb, woutb, out, nullptr,
                                             4096, 2048, 2048, 8);
}

// Round 15
// 242.776 us; speedup vs baseline: 1.1467x; 1.0859x over previous
//
#include <hip/hip_runtime.h>
#include <hip/hip_bf16.h>
#include <stdint.h>

#define T_SEQ 2048
#define D_MODEL 2048
#define N_HEADS 16
#define HEAD_DIM 128

typedef __hip_bfloat16 bf16_t;
typedef __attribute__((ext_vector_type(8))) short short8;
typedef __attribute__((ext_vector_type(4))) short short4v;
typedef __attribute__((ext_vector_type(4))) float f32x4;
typedef __attribute__((ext_vector_type(16))) float f32x16;

__device__ __forceinline__ unsigned short f2bf(float x) {
  union { float f; unsigned u; } c; c.f = x;
  unsigned u = c.u;
  u += 0x7fffu + ((u >> 16) & 1u);   // RNE
  return (unsigned short)(u >> 16);
}
__device__ __forceinline__ float bf2f(short v) {
  union { unsigned u; float f; } c;
  c.u = ((unsigned)(unsigned short)v) << 16;
  return c.f;
}
__device__ __forceinline__ void async16(const bf16_t* g, bf16_t* l) {
  __builtin_amdgcn_global_load_lds(
      (const __attribute__((address_space(1))) void*)g,
      (__attribute__((address_space(3))) void*)l, 16, 0, 0);
}

// ---------------- fused f32 -> bf16 conversion (x, Wqkv, Wout in one launch) ----------------
__global__ __launch_bounds__(256) void cvt3_kernel(
    const float* __restrict__ x, const float* __restrict__ wqkv,
    const float* __restrict__ wout,
    unsigned short* __restrict__ xb, unsigned short* __restrict__ wqkvb,
    unsigned short* __restrict__ woutb) {
  const int N1 = 4096 * 2048 / 4;
  const int N2 = 6144 * 2048 / 4;
  const int N3 = 2048 * 2048 / 4;
  const int total = N1 + N2 + N3;
  for (int i = blockIdx.x * 256 + threadIdx.x; i < total; i += gridDim.x * 256) {
    const float* src; unsigned short* dst; int j;
    if (i < N1)            { src = x;    dst = xb;    j = i; }
    else if (i < N1 + N2)  { src = wqkv; dst = wqkvb; j = i - N1; }
    else                   { src = wout; dst = woutb; j = i - N1 - N2; }
    float4 v = ((const float4*)src)[j];
    short4v o;
    o[0] = (short)f2bf(v.x); o[1] = (short)f2bf(v.y);
    o[2] = (short)f2bf(v.z); o[3] = (short)f2bf(v.w);
    ((short4v*)dst)[j] = o;
  }
}

// ---------------- GEMM C[M,N] = A[M,K] * B[N,K]^T, 128x256 tile ----------------
// Round-5 main loop verbatim (115 us QKV, 0 bank conflicts, 2 blocks/CU).
// MODE 0: f32 direct C write (out-proj).
// MODE 1: fused RoPE/split/V-transpose epilogue (QKV): each N-block lies
//   entirely in Q, K, or V (boundaries at 2048/4096 are multiples of 256);
//   each M-block lies in one batch. Q/K: LDS [128][264] row-major -> rope
//   pairs (hd, hd^64) read as b128 -> coalesced q/k[bh][t][hd] stores.
//   V: LDS [256][136] transposed (b64 packed C-writes) -> contiguous b128
//   reads along t -> coalesced vT[bh][hd][t] stores. Numerics identical to
//   the unfused path (bf16-round -> f32 rope -> bf16-round).
template<int MODE>
__global__ __launch_bounds__(512, 4) void gemm_tp_kernel(
    const bf16_t* __restrict__ A, const bf16_t* __restrict__ Bm,
    float* __restrict__ Cf,
    const float* __restrict__ cosb, const float* __restrict__ sinb,
    bf16_t* __restrict__ qo, bf16_t* __restrict__ ko, bf16_t* __restrict__ vT,
    int M, int N, int K, int nbn) {
  __shared__ bf16_t lds[36864];   // 72 KB: 3x12288 ring; reused by epilogue
  const int tid = threadIdx.x;
  const int w = tid >> 6, lane = tid & 63;
  const int wm = w >> 2, wn = w & 3;
  const int l15 = lane & 15, g = lane >> 4;

  const int nwg = gridDim.x;
  const int cpx = nwg >> 3;
  const int wg = (blockIdx.x & 7) * cpx + (blockIdx.x >> 3);
  const int bm0 = (wg / nbn) * 128, bn0 = (wg % nbn) * 256;

  const int sl = tid >> 3;
  const int su = (tid & 7) ^ (sl & 7);
  const int srow = (sl << 1) | (su >> 2);
  const int sc8 = su & 3;
  const bf16_t* agA = A + (size_t)(bm0 + srow) * K + sc8 * 8;
  const bf16_t* agB = Bm + (size_t)(bn0 + srow) * K + sc8 * 8;

#define STAGE(KT, SB) do {                                                    \
    bf16_t* _d = lds + (SB) * 12288 + w * 512;                                \
    async16(agA + (size_t)(KT) * 32, _d);                                     \
    async16(agB + (size_t)(KT) * 32, _d + 4096);                              \
    async16(agB + 128 * (size_t)K + (size_t)(KT) * 32, _d + 8192);            \
  } while (0)

  const int lhalf = l15 >> 1;
  const int aoff = lhalf * 64 + (((((l15 & 1) << 2) | g) ^ lhalf)) * 8;
  const bf16_t* Abase = lds + wm * 2048 + aoff;
  const bf16_t* Bbase = lds + 4096 + wn * 2048 + aoff;

  f32x4 acc[4][4];
#pragma unroll
  for (int i = 0; i < 4; ++i)
#pragma unroll
    for (int j = 0; j < 4; ++j)
#pragma unroll
      for (int e = 0; e < 4; ++e) acc[i][j][e] = 0.0f;

  STAGE(0, 0);
  STAGE(1, 1);

  const int NT = K >> 5;
  int cb = 0, sb = 2;
  for (int kt = 0; kt < NT - 1; ++kt) {
    asm volatile("s_waitcnt vmcnt(3)" ::: "memory");
    __builtin_amdgcn_s_barrier();
    const bf16_t* Ab = Abase + cb * 12288;
    const bf16_t* Bb = Bbase + cb * 12288;
    short8 af[4], bfr[4];
#pragma unroll
    for (int mi = 0; mi < 4; ++mi) af[mi] = *(const short8*)(Ab + mi * 512);
#pragma unroll
    for (int ni = 0; ni < 4; ++ni) bfr[ni] = *(const short8*)(Bb + ni * 512);
    if (kt < NT - 2) STAGE(kt + 2, sb);
    __builtin_amdgcn_s_setprio(1);
#pragma unroll
    for (int mi = 0; mi < 4; ++mi)
#pragma unroll
      for (int ni = 0; ni < 4; ++ni)
        acc[mi][ni] = __builtin_amdgcn_mfma_f32_16x16x32_bf16(
            af[mi], bfr[ni], acc[mi][ni], 0, 0, 0);
    __builtin_amdgcn_s_setprio(0);
    cb = (cb == 2) ? 0 : cb + 1;
    sb = (sb == 2) ? 0 : sb + 1;
  }
  {
    asm volatile("s_waitcnt vmcnt(0)" ::: "memory");
    __builtin_amdgcn_s_barrier();
    const bf16_t* Ab = Abase + cb * 12288;
    const bf16_t* Bb = Bbase + cb * 12288;
    short8 af[4], bfr[4];
#pragma unroll
    for (int mi = 0; mi < 4; ++mi) af[mi] = *(const short8*)(Ab + mi * 512);
#pragma unroll
    for (int ni = 0; ni < 4; ++ni) bfr[ni] = *(const short8*)(Bb + ni * 512);
    __builtin_amdgcn_s_setprio(1);
#pragma unroll
    for (int mi = 0; mi < 4; ++mi)
#pragma unroll
      for (int ni = 0; ni < 4; ++ni)
        acc[mi][ni] = __builtin_amdgcn_mfma_f32_16x16x32_bf16(
            af[mi], bfr[ni], acc[mi][ni], 0, 0, 0);
    __builtin_amdgcn_s_setprio(0);
  }
#undef STAGE

  if (MODE == 0) {
    // ---- out-proj epilogue: direct f32 stores ----
#pragma unroll
    for (int mi = 0; mi < 4; ++mi)
#pragma unroll
      for (int ni = 0; ni < 4; ++ni)
#pragma unroll
        for (int r = 0; r < 4; ++r) {
          int mr = bm0 + wm * 64 + mi * 16 + g * 4 + r;
          int nc = bn0 + wn * 64 + ni * 16 + l15;
          Cf[(size_t)mr * N + nc] = acc[mi][ni][r];
        }
    return;
  }

  // ---- MODE 1: fused RoPE / split / V-transpose epilogue ----
  const int region = bn0 >> 11;      // 0=Q, 1=K, 2=V (block entirely inside)
  const int bb = bm0 >> 11;          // batch
  const int t0 = bm0 & 2047;         // token base
  __syncthreads();                   // main-loop LDS reads done in all waves

  if (region < 2) {
    // LDS [128][264] row-major (528B rows: 16B-aligned b128 reads)
#pragma unroll
    for (int mi = 0; mi < 4; ++mi)
#pragma unroll
      for (int ni = 0; ni < 4; ++ni)
#pragma unroll
        for (int r = 0; r < 4; ++r) {
          int lr = wm * 64 + mi * 16 + g * 4 + r;
          int lc = wn * 64 + ni * 16 + l15;
          *(unsigned short*)&lds[lr * 264 + lc] = f2bf(acc[mi][ni][r]);
        }
    __syncthreads();

    const float SC = (region == 0) ? 0.08838834764831845f : 1.0f;
    bf16_t* outp = (region == 0) ? qo : ko;
#pragma unroll
    for (int it = 0; it < 8; ++it) {
      int item = it * 512 + tid;         // 4096 = 128 rows x 32 chunks
      int row = item >> 5;
      int col = (item & 31) * 8;
      int cg = (bn0 & 2047) + col;
      int h = cg >> 7, hd = cg & 127;
      int t = t0 + row;
      short8 u  = *(const short8*)&lds[row * 264 + col];
      short8 up = *(const short8*)&lds[row * 264 + ((hd & 64) ? col - 64 : col + 64)];
      const float* cp = cosb + (size_t)t * HEAD_DIM + hd;
      const float* sp = sinb + (size_t)t * HEAD_DIM + hd;
      float4 c0 = *(const float4*)cp, c1 = *(const float4*)(cp + 4);
      float4 s0 = *(const float4*)sp, s1 = *(const float4*)(sp + 4);
      float cs[8] = {c0.x, c0.y, c0.z, c0.w, c1.x, c1.y, c1.z, c1.w};
      float sn[8] = {s0.x, s0.y, s0.z, s0.w, s1.x, s1.y, s1.z, s1.w};
      short8 o;
#pragma unroll
      for (int e = 0; e < 8; ++e) {
        float xl = bf2f(u[e]), xp = bf2f(up[e]);
        float res = (hd & 64) ? (xl * cs[e] + xp * sn[e])
                              : (xl * cs[e] - xp * sn[e]);
        o[e] = (short)f2bf(res * SC);
      }
      *(short8*)(outp + ((size_t)(bb * 16 + h) * T_SEQ + t) * HEAD_DIM + hd) = o;
    }
  } else {
    // V: LDS [256][136] transposed (hd-major); b64 packed C-writes
#pragma unroll
    for (int mi = 0; mi < 4; ++mi)
#pragma unroll
      for (int ni = 0; ni < 4; ++ni) {
        int lc = wn * 64 + ni * 16 + l15;
        int lr = wm * 64 + mi * 16 + g * 4;
        short4v p;
        p[0] = (short)f2bf(acc[mi][ni][0]);
        p[1] = (short)f2bf(acc[mi][ni][1]);
        p[2] = (short)f2bf(acc[mi][ni][2]);
        p[3] = (short)f2bf(acc[mi][ni][3]);
        *(short4v*)&lds[lc * 136 + lr] = p;
      }
    __syncthreads();

#pragma unroll
    for (int it = 0; it < 8; ++it) {
      int item = it * 512 + tid;         // 4096 = 256 cols x 16 t-chunks
      int col = item >> 4;
      int tch = (item & 15) * 8;
      short8 v = *(const short8*)&lds[col * 136 + tch];
      int cg = (bn0 & 2047) + col;
      int h = cg >> 7, hd = cg & 127;
      *(short8*)(vT + ((size_t)(bb * 16 + h) * HEAD_DIM + hd) * T_SEQ + t0 + tch) = v;
    }
  }
}

// ---------------- causal flash attention: swapped-QK^T 32x32, in-reg softmax ----
// (round-13/14 version: in-reg softmax + T13 defer-max; passed at ~80 us)
__global__ __launch_bounds__(256, 2) void attn_kernel(
    const bf16_t* __restrict__ q, const bf16_t* __restrict__ k,
    const bf16_t* __restrict__ vT, unsigned short* __restrict__ attn) {
  const int bx = blockIdx.x;
  const int bh = bx & 31;
  const int qi = (bx >> 5) & 7;
  const int qt = (bx >> 8) ? qi : 15 - qi;
  const int b = bh / N_HEADS, h = bh % N_HEADS;
  const int tid = threadIdx.x;
  const int w = tid >> 6, lane = tid & 63;
  const int l31 = lane & 31, hi = lane >> 5;
  const int swz = l31 & 7;
  const float LOG2E = 1.44269504088896340736f;

  __shared__ bf16_t smem[32768];

  const bf16_t* qb = q + (size_t)bh * T_SEQ * HEAD_DIM;
  const bf16_t* kb = k + (size_t)bh * T_SEQ * HEAD_DIM;
  const bf16_t* vb = vT + (size_t)bh * HEAD_DIM * T_SEQ;

  const int qlo = qt * 128 + w * 32;
  const int qhi = qlo + 31;
  const int qrow = qlo + l31;

  short8 qf[8];
#pragma unroll
  for (int ks = 0; ks < 8; ++ks)
    qf[ks] = *(const short8*)(qb + (size_t)qrow * HEAD_DIM + ks * 16 + hi * 8);

  float m = -3.0e38f, l = 0.0f;
  f32x16 O[4];
#pragma unroll
  for (int dt = 0; dt < 4; ++dt)
#pragma unroll
    for (int r = 0; r < 16; ++r) O[dt][r] = 0.0f;

#define STAGE_TILES(KT, BU) {                                                    \
    _Pragma("unroll")                                                            \
    for (int j = 0; j < 4; ++j) {                                                \
      int s = j * 4 + w;                                                         \
      int row = s * 4 + (lane >> 4);                                             \
      int gc = (lane & 15) ^ (row & 7);                                          \
      async16(kb + (size_t)((KT) * 64 + row) * HEAD_DIM + gc * 8,                \
              smem + (BU) * 8192 + s * 512);                                     \
    }                                                                            \
    _Pragma("unroll")                                                            \
    for (int j = 0; j < 4; ++j) {                                                \
      int s = j * 4 + w;                                                         \
      int row = s * 8 + (lane >> 3);                                             \
      int gc = (lane & 7) ^ (row & 7);                                           \
      async16(vb + (size_t)row * T_SEQ + (KT) * 64 + gc * 8,                     \
              smem + 16384 + (BU) * 8192 + s * 512);                             \
    }                                                                            \
  }

  STAGE_TILES(0, 0);
  __syncthreads();
  int buf = 0;

  const int lastk = 2 * qt + 1;
  for (int kt = 0; kt <= lastk; ++kt) {
    if (kt < lastk) STAGE_TILES(kt + 1, buf ^ 1);
    const bf16_t* Ks = smem + buf * 8192;
    const bf16_t* Vs = smem + 16384 + buf * 8192;
    const bool active = (kt * 64 <= qhi);

    if (active) {
      f32x16 S[2];
#pragma unroll
      for (int kvt = 0; kvt < 2; ++kvt) {
        const int kvbase = kt * 64 + kvt * 32;
        if (kvbase <= qhi) {
          const int krow = kvt * 32 + l31;
#pragma unroll
          for (int r = 0; r < 16; ++r) S[kvt][r] = 0.0f;
          __builtin_amdgcn_s_setprio(1);
#pragma unroll
          for (int ks = 0; ks < 8; ++ks) {
            int c = (2 * ks + hi) ^ swz;
            short8 kf = *(const short8*)(Ks + krow * 128 + c * 8);
            S[kvt] = __builtin_amdgcn_mfma_f32_32x32x16_bf16(kf, qf[ks], S[kvt], 0, 0, 0);
          }
          __builtin_amdgcn_s_setprio(0);
          if (kvbase + 31 > qlo) {
#pragma unroll
            for (int r = 0; r < 16; ++r) {
              int kv = kvbase + (r & 3) + 8 * (r >> 2) + 4 * hi;
              if (kv > qrow) S[kvt][r] = -3.0e38f;
            }
          }
        } else {
#pragma unroll
          for (int r = 0; r < 16; ++r) S[kvt][r] = -3.0e38f;
        }
      }

      // ---- in-register online softmax with defer-max (T13) ----
      float rl = -3.0e38f;
#pragma unroll
      for (int kvt = 0; kvt < 2; ++kvt)
#pragma unroll
        for (int r = 0; r < 16; ++r) rl = fmaxf(rl, S[kvt][r]);
      rl = fmaxf(rl, __shfl_xor(rl, 32, 64));
      const bool defer = __all(rl <= m + 8.0f) != 0;
      if (!defer) {
        float mn = fmaxf(m, rl);
        float fac = exp2f((m - mn) * LOG2E);
        m = mn;
        l *= fac;
#pragma unroll
        for (int dt = 0; dt < 4; ++dt)
#pragma unroll
          for (int r = 0; r < 16; ++r) O[dt][r] *= fac;
      }
      float sum = 0.0f;
#pragma unroll
      for (int kvt = 0; kvt < 2; ++kvt)
#pragma unroll
        for (int r = 0; r < 16; ++r) {
          float p = exp2f((S[kvt][r] - m) * LOG2E);
          S[kvt][r] = p;
          sum += p;
        }
      sum += __shfl_xor(sum, 32, 64);
      l += sum;

      short8 pf[4];
#pragma unroll
      for (int ks = 0; ks < 4; ++ks) {
        const int kvt = ks >> 1;
        const int base = (ks & 1) * 8;
        unsigned pkL0, pkL1, pkH0, pkH1;
        {
          float a0 = S[kvt][base + 0], a1 = S[kvt][base + 1];
          float a2 = S[kvt][base + 2], a3 = S[kvt][base + 3];
          float b0 = S[kvt][base + 4], b1 = S[kvt][base + 5];
          float b2 = S[kvt][base + 6], b3 = S[kvt][base + 7];
          asm("v_cvt_pk_bf16_f32 %0, %1, %2" : "=v"(pkL0) : "v"(a0), "v"(a1));
          asm("v_cvt_pk_bf16_f32 %0, %1, %2" : "=v"(pkL1) : "v"(a2), "v"(a3));
          asm("v_cvt_pk_bf16_f32 %0, %1, %2" : "=v"(pkH0) : "v"(b0), "v"(b1));
          asm("v_cvt_pk_bf16_f32 %0, %1, %2" : "=v"(pkH1) : "v"(b2), "v"(b3));
        }
        unsigned sx0 = hi ? pkL0 : pkH0;
        unsigned sx1 = hi ? pkL1 : pkH1;
        unsigned rx0 = (unsigned)__shfl_xor((int)sx0, 32, 64);
        unsigned rx1 = (unsigned)__shfl_xor((int)sx1, 32, 64);
        union { unsigned u[4]; short8 s; } uu;
        uu.u[0] = hi ? rx0 : pkL0;
        uu.u[1] = hi ? rx1 : pkL1;
        uu.u[2] = hi ? pkH0 : rx0;
        uu.u[3] = hi ? pkH1 : rx1;
        pf[ks] = uu.s;
      }

      __builtin_amdgcn_s_setprio(1);
#pragma unroll
      for (int dt = 0; dt < 4; ++dt) {
        const int vrow = dt * 32 + l31;
#pragma unroll
        for (int ks = 0; ks < 4; ++ks) {
          int c = (2 * ks + hi) ^ swz;
          short8 vf = *(const short8*)(Vs + vrow * 64 + c * 8);
          O[dt] = __builtin_amdgcn_mfma_f32_32x32x16_bf16(vf, pf[ks], O[dt], 0, 0, 0);
        }
      }
      __builtin_amdgcn_s_setprio(0);
    }

    __syncthreads();
    buf ^= 1;
  }
#undef STAGE_TILES

  float inv = 1.0f / l;
  bf16_t* ol = smem + w * 4352;
#pragma unroll
  for (int dt = 0; dt < 4; ++dt)
#pragma unroll
    for (int r = 0; r < 16; ++r) {
      int d = dt * 32 + (r & 3) + 8 * (r >> 2) + 4 * hi;
      *(unsigned short*)&ol[l31 * 136 + d] = f2bf(O[dt][r] * inv);
    }
  __syncthreads();
  const int srow4 = lane >> 4;
  const int scol = (lane & 15) * 8;
#pragma unroll
  for (int rr = 0; rr < 8; ++rr) {
    int row = rr * 4 + srow4;
    short8 v = *(const short8*)(ol + row * 136 + scol);
    *(short8*)(attn + ((size_t)b * T_SEQ + qt * 128 + w * 32 + row) * D_MODEL +
               (size_t)h * HEAD_DIM + scol) = v;
  }
}

// ---------------- launch ----------------
extern "C" void kernel_launch(void* const* d_in, const int* in_sizes, int n_in,
                              void* d_out, int out_size, void* d_ws, size_t ws_size,
                              hipStream_t stream) {
  const float* x    = (const float*)d_in[0];
  const float* cosb = (const float*)d_in[1];
  const float* sinb = (const float*)d_in[2];
  const float* Wqkv = (const float*)d_in[3];
  const float* Wout = (const float*)d_in[4];
  float* out = (float*)d_out;

  char* ws = (char*)d_ws;
  size_t off = 0;
  bf16_t* xb    = (bf16_t*)(ws + off); off += (size_t)4096 * 2048 * 2;
  bf16_t* wqkvb = (bf16_t*)(ws + off); off += (size_t)6144 * 2048 * 2;
  bf16_t* woutb = (bf16_t*)(ws + off); off += (size_t)2048 * 2048 * 2;
  bf16_t* qb    = (bf16_t*)(ws + off); off += (size_t)32 * 2048 * 128 * 2;
  bf16_t* kb    = (bf16_t*)(ws + off); off += (size_t)32 * 2048 * 128 * 2;
  bf16_t* vTb   = (bf16_t*)(ws + off); off += (size_t)32 * 2048 * 128 * 2;
  bf16_t* attnb = xb;  // xb dead after QKV GEMM

  cvt3_kernel<<<2048, 256, 0, stream>>>(x, Wqkv, Wout,
                                        (unsigned short*)xb, (unsigned short*)wqkvb,
                                        (unsigned short*)woutb);

  // QKV + fused RoPE/split/V-transpose: 32x24 = 768 blocks
  gemm_tp_kernel<1><<<768, 512, 0, stream>>>(xb, wqkvb, nullptr, cosb, sinb,
                                             qb, kb, vTb, 4096, 6144, 2048, 24);

  // 512 blocks: 32 bh x 16 q-tiles of 128 rows; 2 blocks/CU, paired workloads
  attn_kernel<<<512, 256, 0, stream>>>(qb, kb, vTb, (unsigned short*)attnb);

  // out-proj: 32x8 = 256 blocks
  gemm_tp_kernel<0><<<256, 512, 0, stream>>>(attnb, woutb, out, nullptr, nullptr,
                                             nullptr, nullptr, nullptr,
                                             4096, 2048, 2048, 8);
}